// Round 6
// baseline (162.342 us; speedup 1.0000x reference)
//
#include <hip/hip_runtime.h>
#include <hip/hip_bf16.h>

typedef unsigned int u32;
typedef unsigned short u16;
typedef __attribute__((ext_vector_type(8))) __bf16 bf16x8;
typedef __attribute__((ext_vector_type(16))) float f32x16;
typedef __attribute__((ext_vector_type(2))) unsigned int u32x2;

// log2(e)/sqrt(32): folds exp->exp2 and 1/sqrt(rank) into Q.
#define QSCALE 0.25505418f
#define MFMA __builtin_amdgcn_mfma_f32_32x32x16_bf16

static __device__ __forceinline__ u16 f2b(float f) {
  __hip_bfloat16 h = __float2bfloat16(f);
  return *reinterpret_cast<u16*>(&h);
}
// HW packed f32->bf16 (RNE). Single VALU instr vs ~6-op SW emulation.
static __device__ __forceinline__ u32 cvtpk(float lo, float hi) {
  u32 r;
  asm("v_cvt_pk_bf16_f32 %0, %1, %2" : "=v"(r) : "v"(lo), "v"(hi));
  return r;
}

static __device__ __forceinline__ float xhalf_sum(float v) {
#if __has_builtin(__builtin_amdgcn_permlane32_swap)
  u32 a = __float_as_uint(v);
  u32x2 r = __builtin_amdgcn_permlane32_swap(a, a, false, false);
  return __uint_as_float(r[0]) + __uint_as_float(r[1]);
#else
  return v + __shfl_xor(v, 32);
#endif
}

// tau: involution on [0,32): swap bits 0,1 of the 4-group index.
// VT columns stored in tau order so P-regs feed the PV B-fragment directly.
static __device__ __forceinline__ int tau(int p) {
  int g = p >> 2;
  int gk = (g & 4) | ((g & 1) << 1) | ((g >> 1) & 1);
  return (gk << 2) | (p & 3);
}

// ---------------------------------------------------------------------------
// K1: fold weights. WQT/WKT/WVT[h][r][rp] (bf16, pre-transposed for A-frags),
// BQKV f32 (bq|bk|bv), WOT[r2][hr] bf16, UT[r][k]=qkv_u^T bf16,
// OVT[d][r]=out_v^T bf16.
// ---------------------------------------------------------------------------
__global__ __launch_bounds__(256) void k_prep(const float* __restrict__ qkv_v,
                                              const float* __restrict__ qkv_b,
                                              const float* __restrict__ u_attn,
                                              const float* __restrict__ v_attn,
                                              const float* __restrict__ out_u,
                                              const float* __restrict__ qkv_u,
                                              const float* __restrict__ out_v,
                                              u16* __restrict__ WQT, u16* __restrict__ WKT,
                                              u16* __restrict__ WVT, float* __restrict__ BQKV,
                                              u16* __restrict__ WOT, u16* __restrict__ UT,
                                              u16* __restrict__ OVT) {
  int blk = blockIdx.x;
  int tid = threadIdx.x;
  if (blk < 16) {
    int h = blk;
    int r = tid & 31, g = tid >> 5;
    for (int rp = g; rp < 32; rp += 8) {
      float aq = 0.f, ak = 0.f, av = 0.f;
      for (int d = 0; d < 64; ++d) {
        float u = u_attn[(h * 64 + d) * 32 + r];
        aq += qkv_v[rp * 3072 + h * 64 + d] * u;
        ak += qkv_v[rp * 3072 + 1024 + h * 64 + d] * u;
        av += qkv_v[rp * 3072 + 2048 + h * 64 + d] * u;
      }
      WQT[(h * 32 + r) * 32 + rp] = f2b(aq);
      WKT[(h * 32 + r) * 32 + rp] = f2b(ak);
      WVT[(h * 32 + r) * 32 + rp] = f2b(av);
    }
    for (int rr = g; rr < 32; rr += 8) {
      float a = 0.f;
      for (int d = 0; d < 64; ++d)
        a += v_attn[(h * 32 + rr) * 64 + d] * out_u[(h * 64 + d) * 32 + r];
      WOT[r * 512 + h * 32 + rr] = f2b(a);
    }
    if (tid < 32) {
      float aq = 0.f, ak = 0.f, av = 0.f;
      for (int d = 0; d < 64; ++d) {
        float u = u_attn[(h * 64 + d) * 32 + r];
        aq += qkv_b[h * 64 + d] * u;
        ak += qkv_b[1024 + h * 64 + d] * u;
        av += qkv_b[2048 + h * 64 + d] * u;
      }
      BQKV[h * 32 + r] = aq;
      BQKV[512 + h * 32 + r] = ak;
      BQKV[1024 + h * 32 + r] = av;
    }
  } else if (blk < 24) {
    int kb = (blk - 16) * 128;
    for (int i = tid; i < 4096; i += 256) {
      int r = i >> 7, kl = i & 127;
      UT[r * 1024 + kb + kl] = f2b(qkv_u[(kb + kl) * 32 + r]);
    }
  } else {
    int db = (blk - 24) * 128;
    for (int i = tid; i < 4096; i += 256) {
      int dl = i >> 5, r = i & 31;
      OVT[(db + dl) * 32 + r] = f2b(out_v[r * 1024 + db + dl]);
    }
  }
}

// ---------------------------------------------------------------------------
// K2: T = x @ qkv_u -> bf16 [8192][32]. MFMA, block = 32-row tile, 4 waves
// split K (256 each, 16 steps), LDS reduce.
// ---------------------------------------------------------------------------
__global__ __launch_bounds__(256) void k_proj(const float* __restrict__ x,
                                              const u16* __restrict__ UT,
                                              u16* __restrict__ T) {
  __shared__ float red[4][32][33];
  int tid = threadIdx.x;
  int w = tid >> 6, l = tid & 63, lo = l & 31, hi = l >> 5;
  int m0 = blockIdx.x * 32;
  const float* xp = x + (size_t)(m0 + lo) * 1024 + w * 256 + hi * 8;
  const u16* up = UT + lo * 1024 + w * 256 + hi * 8;
  f32x16 acc = {};
  for (int s = 0; s < 16; ++s) {
    float4 x0 = *(const float4*)(xp);
    float4 x1 = *(const float4*)(xp + 4);
    xp += 16;
    union { bf16x8 v; u32 u[4]; } af;
    af.u[0] = cvtpk(x0.x, x0.y);
    af.u[1] = cvtpk(x0.z, x0.w);
    af.u[2] = cvtpk(x1.x, x1.y);
    af.u[3] = cvtpk(x1.z, x1.w);
    bf16x8 bf = *(const bf16x8*)(up);
    up += 16;
    acc = MFMA(af.v, bf, acc, 0, 0, 0);
  }
#pragma unroll
  for (int i = 0; i < 16; ++i)
    red[w][(i & 3) + 8 * (i >> 2) + 4 * hi][lo] = acc[i];
  __syncthreads();
  int m = tid >> 3, c = (tid & 7) * 4;
  float v0 = red[0][m][c + 0] + red[1][m][c + 0] + red[2][m][c + 0] + red[3][m][c + 0];
  float v1 = red[0][m][c + 1] + red[1][m][c + 1] + red[2][m][c + 1] + red[3][m][c + 1];
  float v2 = red[0][m][c + 2] + red[1][m][c + 2] + red[2][m][c + 2] + red[3][m][c + 2];
  float v3 = red[0][m][c + 3] + red[1][m][c + 3] + red[2][m][c + 3] + red[3][m][c + 3];
  uint2 o;
  o.x = cvtpk(v0, v1);
  o.y = cvtpk(v2, v3);
  *(uint2*)(T + (size_t)(m0 + m) * 32 + c) = o;
}

// ---------------------------------------------------------------------------
// K3: per-head low-rank Q/K/V via MFMA. Wave = one 32-s tile; 6 MFMAs.
// QL/KL [bh][s][32] bf16 (Q scaled), VT [bh][32][s] via LDS transpose.
// VT columns are tau-permuted within each 32-key tile (see k_attn).
// ---------------------------------------------------------------------------
__global__ __launch_bounds__(256) void k_lowproj(const u16* __restrict__ T,
                                                 const u16* __restrict__ WQT,
                                                 const u16* __restrict__ WKT,
                                                 const u16* __restrict__ WVT,
                                                 const float* __restrict__ BQKV,
                                                 u16* __restrict__ QL, u16* __restrict__ KL,
                                                 u16* __restrict__ VT) {
  __shared__ float vtf[32][132];
  int tid = threadIdx.x;
  int w = tid >> 6, l = tid & 63, lo = l & 31, hi = l >> 5;
  int blk = blockIdx.x;  // 64 bh * 16 sblocks
  int bh = blk >> 4, sb = (blk & 15) * 128;
  int b = bh >> 4, h = bh & 15;
  int s0 = sb + w * 32;

  const u16* wq = WQT + (h * 32 + lo) * 32 + hi * 8;
  const u16* wk = WKT + (h * 32 + lo) * 32 + hi * 8;
  const u16* wv = WVT + (h * 32 + lo) * 32 + hi * 8;
  bf16x8 aq0 = *(const bf16x8*)(wq), aq1 = *(const bf16x8*)(wq + 16);
  bf16x8 ak0 = *(const bf16x8*)(wk), ak1 = *(const bf16x8*)(wk + 16);
  bf16x8 av0 = *(const bf16x8*)(wv), av1 = *(const bf16x8*)(wv + 16);

  const u16* tp = T + (size_t)(b * 2048 + s0 + lo) * 32 + hi * 8;
  bf16x8 tb0 = *(const bf16x8*)(tp), tb1 = *(const bf16x8*)(tp + 16);

  f32x16 cq = {}, ck = {}, cv = {};
  cq = MFMA(aq0, tb0, cq, 0, 0, 0);
  cq = MFMA(aq1, tb1, cq, 0, 0, 0);
  ck = MFMA(ak0, tb0, ck, 0, 0, 0);
  ck = MFMA(ak1, tb1, ck, 0, 0, 0);
  cv = MFMA(av0, tb0, cv, 0, 0, 0);
  cv = MFMA(av1, tb1, cv, 0, 0, 0);

  size_t sg = (size_t)bh * 2048 + s0 + lo;
  int slp = w * 32 + tau(lo);
#pragma unroll
  for (int g2 = 0; g2 < 4; ++g2) {
    float4 bq4 = *(const float4*)(BQKV + h * 32 + g2 * 8 + 4 * hi);
    float4 bk4 = *(const float4*)(BQKV + 512 + h * 32 + g2 * 8 + 4 * hi);
    float4 bv4 = *(const float4*)(BQKV + 1024 + h * 32 + g2 * 8 + 4 * hi);
    float q0 = (cq[4 * g2 + 0] + bq4.x) * QSCALE;
    float q1 = (cq[4 * g2 + 1] + bq4.y) * QSCALE;
    float q2 = (cq[4 * g2 + 2] + bq4.z) * QSCALE;
    float q3 = (cq[4 * g2 + 3] + bq4.w) * QSCALE;
    uint2 qo; qo.x = cvtpk(q0, q1); qo.y = cvtpk(q2, q3);
    *(uint2*)(QL + sg * 32 + g2 * 8 + 4 * hi) = qo;
    uint2 ko;
    ko.x = cvtpk(ck[4 * g2 + 0] + bk4.x, ck[4 * g2 + 1] + bk4.y);
    ko.y = cvtpk(ck[4 * g2 + 2] + bk4.z, ck[4 * g2 + 3] + bk4.w);
    *(uint2*)(KL + sg * 32 + g2 * 8 + 4 * hi) = ko;
    int rbase = g2 * 8 + 4 * hi;
    vtf[rbase + 0][slp] = cv[4 * g2 + 0] + bv4.x;
    vtf[rbase + 1][slp] = cv[4 * g2 + 1] + bv4.y;
    vtf[rbase + 2][slp] = cv[4 * g2 + 2] + bv4.z;
    vtf[rbase + 3][slp] = cv[4 * g2 + 3] + bv4.w;
  }
  __syncthreads();
  for (int u = tid; u < 512; u += 256) {
    int r = u >> 4, su = (u & 15) * 8;
    const float* src = &vtf[r][su];
    uint4 o;
    o.x = cvtpk(src[0], src[1]);
    o.y = cvtpk(src[2], src[3]);
    o.z = cvtpk(src[4], src[5]);
    o.w = cvtpk(src[6], src[7]);
    *(uint4*)(VT + ((size_t)bh * 32 + r) * 2048 + sb + su) = o;
  }
}

// ---------------------------------------------------------------------------
// K4: flash attention (swapped-operand 32x32x16 MFMA).
// Fixed-base softmax -> K-partials are ADDITIVE (no max/rescale), so split
// the 64 key-tiles across 2 waves (32 each) and combine once via LDS.
// r5 was latency-bound at 4 waves/SIMD (grid-limited occupancy 41%, all
// pipes <32% busy); this doubles resident waves to 8/SIMD (VGPR 56 <= 64).
// Block = 2 q-tiles x 2 K-halves; grid 2048 = 64 bh x 32 q-pairs.
// XCD swizzle: all 32 blocks of one bh land on one XCD -> K/V read into
// each XCD L2 once (bijective since 2048 % 8 == 0).
// VT tau-permutation feeds PV B-frags with zero shuffles; hot loop has
// zero mask work (one-time pre-scan; general masked loop in cold branch).
// ---------------------------------------------------------------------------
__global__ __launch_bounds__(256) void k_attn(const u16* __restrict__ QL,
                                              const u16* __restrict__ KL,
                                              const u16* __restrict__ VT,
                                              const int* __restrict__ mask,
                                              u16* __restrict__ CTX) {
  __shared__ float pacc[2][64][17];
  __shared__ float pl[2][64];
  __shared__ u32 cls[64][17];
  int tid = threadIdx.x;
  int wave = tid >> 6, l = tid & 63, lo = l & 31, hi = l >> 5;
  int blk = blockIdx.x;
  // XCD-aware decode: xcd = blk & 7 (round-robin dispatch), 256 slots/XCD,
  // 8 bh per XCD, 32 q-pairs per bh.
  int xcd = blk & 7, slot = blk >> 3;
  int bh = xcd * 8 + (slot >> 5);
  int qpair = slot & 31;
  int qi = wave & 1;     // q-tile within pair
  int khalf = wave >> 1; // K-half: tiles [khalf*32, khalf*32+32)
  int qt = qpair * 2 + qi;
  int b = bh >> 4, h = bh & 15;

  const int* mk = mask + b * 2048;

  int q = qt * 32 + lo;
  const u16* qp = QL + (size_t)bh * 65536 + q * 32 + hi * 8;
  bf16x8 qb0 = *(const bf16x8*)(qp);
  bf16x8 qb1 = *(const bf16x8*)(qp + 16);

  const u16* kp = KL + (size_t)bh * 65536 + (size_t)khalf * 32768 + (size_t)lo * 32 + hi * 8;
  const u16* vp = VT + (size_t)bh * 65536 + (size_t)lo * 2048 + khalf * 1024 + hi * 8;

  f32x16 acc = {};
  float l_run = 0.f;

  // one-time mask pre-scan: is every key unmasked?
  int mall = 1;
  for (int i = l; i < 2048; i += 64) mall &= (mk[i] != 0) ? 1 : 0;

  if (__all(mall)) {
    // hot path: no mask loads, no ballot
#pragma unroll 1
    for (int kt = 0; kt < 32; ++kt) {
      bf16x8 ka0 = *(const bf16x8*)(kp);
      bf16x8 ka1 = *(const bf16x8*)(kp + 16);
      kp += 1024;
      f32x16 sc = {};
      sc = MFMA(ka0, qb0, sc, 0, 0, 0);
      sc = MFMA(ka1, qb1, sc, 0, 0, 0);
      bf16x8 va0 = *(const bf16x8*)(vp);
      bf16x8 va1 = *(const bf16x8*)(vp + 16);
      vp += 32;
      union { bf16x8 v; u32 u[4]; } fa;
      float a0 = __builtin_amdgcn_exp2f(sc[0]);
      float a1 = __builtin_amdgcn_exp2f(sc[1]);
      float a2 = __builtin_amdgcn_exp2f(sc[2]);
      float a3 = __builtin_amdgcn_exp2f(sc[3]);
      fa.u[0] = cvtpk(a0, a1);
      fa.u[1] = cvtpk(a2, a3);
      float t0 = (a0 + a1) + (a2 + a3);
      a0 = __builtin_amdgcn_exp2f(sc[4]);
      a1 = __builtin_amdgcn_exp2f(sc[5]);
      a2 = __builtin_amdgcn_exp2f(sc[6]);
      a3 = __builtin_amdgcn_exp2f(sc[7]);
      fa.u[2] = cvtpk(a0, a1);
      fa.u[3] = cvtpk(a2, a3);
      float t1 = (a0 + a1) + (a2 + a3);
      acc = MFMA(va0, fa.v, acc, 0, 0, 0);
      union { bf16x8 v; u32 u[4]; } fc;
      a0 = __builtin_amdgcn_exp2f(sc[8]);
      a1 = __builtin_amdgcn_exp2f(sc[9]);
      a2 = __builtin_amdgcn_exp2f(sc[10]);
      a3 = __builtin_amdgcn_exp2f(sc[11]);
      fc.u[0] = cvtpk(a0, a1);
      fc.u[1] = cvtpk(a2, a3);
      float t2 = (a0 + a1) + (a2 + a3);
      a0 = __builtin_amdgcn_exp2f(sc[12]);
      a1 = __builtin_amdgcn_exp2f(sc[13]);
      a2 = __builtin_amdgcn_exp2f(sc[14]);
      a3 = __builtin_amdgcn_exp2f(sc[15]);
      fc.u[2] = cvtpk(a0, a1);
      fc.u[3] = cvtpk(a2, a3);
      float t3 = (a0 + a1) + (a2 + a3);
      acc = MFMA(va1, fc.v, acc, 0, 0, 0);
      l_run += (t0 + t1) + (t2 + t3);
    }
  } else {
    // cold path: general masked loop (per-tile ballot + score clamp)
    const int* mp = mk + khalf * 1024 + lo;
#pragma unroll 1
    for (int kt = 0; kt < 32; ++kt) {
      unsigned long long bm = __ballot(mp[0] != 0);
      mp += 32;
      bf16x8 ka0 = *(const bf16x8*)(kp);
      bf16x8 ka1 = *(const bf16x8*)(kp + 16);
      kp += 1024;
      f32x16 sc = {};
      sc = MFMA(ka0, qb0, sc, 0, 0, 0);
      sc = MFMA(ka1, qb1, sc, 0, 0, 0);
      u32 km = (u32)bm;
#pragma unroll
      for (int i = 0; i < 16; ++i) {
        int key = (i & 3) + 8 * (i >> 2) + 4 * hi;
        if (!((km >> key) & 1)) sc[i] = -3.0e38f;
      }
      bf16x8 va0 = *(const bf16x8*)(vp);
      bf16x8 va1 = *(const bf16x8*)(vp + 16);
      vp += 32;
      union { bf16x8 v; u32 u[4]; } fa;
      float a0 = __builtin_amdgcn_exp2f(sc[0]);
      float a1 = __builtin_amdgcn_exp2f(sc[1]);
      float a2 = __builtin_amdgcn_exp2f(sc[2]);
      float a3 = __builtin_amdgcn_exp2f(sc[3]);
      fa.u[0] = cvtpk(a0, a1);
      fa.u[1] = cvtpk(a2, a3);
      float t0 = (a0 + a1) + (a2 + a3);
      a0 = __builtin_amdgcn_exp2f(sc[4]);
      a1 = __builtin_amdgcn_exp2f(sc[5]);
      a2 = __builtin_amdgcn_exp2f(sc[6]);
      a3 = __builtin_amdgcn_exp2f(sc[7]);
      fa.u[2] = cvtpk(a0, a1);
      fa.u[3] = cvtpk(a2, a3);
      float t1 = (a0 + a1) + (a2 + a3);
      acc = MFMA(va0, fa.v, acc, 0, 0, 0);
      union { bf16x8 v; u32 u[4]; } fc;
      a0 = __builtin_amdgcn_exp2f(sc[8]);
      a1 = __builtin_amdgcn_exp2f(sc[9]);
      a2 = __builtin_amdgcn_exp2f(sc[10]);
      a3 = __builtin_amdgcn_exp2f(sc[11]);
      fc.u[0] = cvtpk(a0, a1);
      fc.u[1] = cvtpk(a2, a3);
      float t2 = (a0 + a1) + (a2 + a3);
      a0 = __builtin_amdgcn_exp2f(sc[12]);
      a1 = __builtin_amdgcn_exp2f(sc[13]);
      a2 = __builtin_amdgcn_exp2f(sc[14]);
      a3 = __builtin_amdgcn_exp2f(sc[15]);
      fc.u[2] = cvtpk(a0, a1);
      fc.u[3] = cvtpk(a2, a3);
      float t3 = (a0 + a1) + (a2 + a3);
      acc = MFMA(va1, fc.v, acc, 0, 0, 0);
      l_run += (t0 + t1) + (t2 + t3);
    }
  }

  // combine K-halves: khalf=1 publishes partials, khalf=0 reduces.
  if (khalf) {
#pragma unroll
    for (int i = 0; i < 16; ++i) pacc[qi][l][i] = acc[i];
    pl[qi][l] = l_run;
  }
  __syncthreads();
  if (!khalf) {
#pragma unroll
    for (int i = 0; i < 16; ++i) acc[i] += pacc[qi][l][i];
    l_run += pl[qi][l];
    l_run = xhalf_sum(l_run);  // other 16 keys of this q live in partner half
    float inv = 1.0f / l_run;
    int qloc = qi * 32 + lo;
#pragma unroll
    for (int g2 = 0; g2 < 4; ++g2) {
      cls[qloc][g2 * 4 + 2 * hi] = cvtpk(acc[4 * g2 + 0] * inv, acc[4 * g2 + 1] * inv);
      cls[qloc][g2 * 4 + 2 * hi + 1] = cvtpk(acc[4 * g2 + 2] * inv, acc[4 * g2 + 3] * inv);
    }
  }
  __syncthreads();
  // write 64 q-rows x 32 bf16: one uint4 per thread
  int s_loc = tid >> 2, quad = tid & 3;
  int srow = qpair * 64 + s_loc;
  const u32* src = &cls[s_loc][quad * 4];
  uint4 v0;
  v0.x = src[0]; v0.y = src[1]; v0.z = src[2]; v0.w = src[3];
  u16* dst = CTX + (((size_t)(b * 2048 + srow)) * 16 + h) * 32 + quad * 8;
  *(uint4*)(dst) = v0;
}

// ---------------------------------------------------------------------------
// K5a: ylow[s][r2] = ctx[s][0:512] @ WOT^T. Block = 32-row tile, 4-way K
// split, LDS reduce, bf16 out.
// ---------------------------------------------------------------------------
__global__ __launch_bounds__(256) void k_epi1(const u16* __restrict__ CTX,
                                              const u16* __restrict__ WOT,
                                              u16* __restrict__ YL) {
  __shared__ float red[4][32][33];
  int tid = threadIdx.x;
  int w = tid >> 6, l = tid & 63, lo = l & 31, hi = l >> 5;
  int s0 = blockIdx.x * 32;
  const u16* cp = CTX + (size_t)(s0 + lo) * 512 + w * 128 + hi * 8;
  const u16* wp = WOT + lo * 512 + w * 128 + hi * 8;
  f32x16 acc = {};
  for (int st = 0; st < 8; ++st) {
    bf16x8 a = *(const bf16x8*)(cp);
    bf16x8 bb = *(const bf16x8*)(wp);
    cp += 16;
    wp += 16;
    acc = MFMA(a, bb, acc, 0, 0, 0);
  }
#pragma unroll
  for (int i = 0; i < 16; ++i)
    red[w][(i & 3) + 8 * (i >> 2) + 4 * hi][lo] = acc[i];
  __syncthreads();
  int m = tid >> 3, c = (tid & 7) * 4;
  float v0 = red[0][m][c + 0] + red[1][m][c + 0] + red[2][m][c + 0] + red[3][m][c + 0];
  float v1 = red[0][m][c + 1] + red[1][m][c + 1] + red[2][m][c + 1] + red[3][m][c + 1];
  float v2 = red[0][m][c + 2] + red[1][m][c + 2] + red[2][m][c + 2] + red[3][m][c + 2];
  float v3 = red[0][m][c + 3] + red[1][m][c + 3] + red[2][m][c + 3] + red[3][m][c + 3];
  uint2 o;
  o.x = cvtpk(v0, v1);
  o.y = cvtpk(v2, v3);
  *(uint2*)(YL + (size_t)(s0 + m) * 32 + c) = o;
}

// ---------------------------------------------------------------------------
// K5b: out = ylow @ out_v + out_b. Block = 32 s x 128 d (4 waves, one d-sub
// tile each), LDS-staged coalesced f32 stores.
// ---------------------------------------------------------------------------
__global__ __launch_bounds__(256) void k_epi2(const u16* __restrict__ YL,
                                              const u16* __restrict__ OVT,
                                              const float* __restrict__ out_b,
                                              float* __restrict__ out) {
  __shared__ float ol[32][133];
  int tid = threadIdx.x;
  int w = tid >> 6, l = tid & 63, lo = l & 31, hi = l >> 5;
  int blk = blockIdx.x;  // 256 s-tiles x 8 d-tiles
  int s0 = (blk >> 3) * 32;
  int d0 = (blk & 7) * 128;
  int dw = d0 + w * 32;
  const u16* ap = OVT + (size_t)(dw + lo) * 32 + hi * 8;
  bf16x8 a0 = *(const bf16x8*)(ap), a1 = *(const bf16x8*)(ap + 16);
  const u16* bp = YL + (size_t)(s0 + lo) * 32 + hi * 8;
  bf16x8 b0 = *(const bf16x8*)(bp), b1 = *(const bf16x8*)(bp + 16);
  f32x16 acc = {};
  acc = MFMA(a0, b0, acc, 0, 0, 0);
  acc = MFMA(a1, b1, acc, 0, 0, 0);
#pragma unroll
  for (int i = 0; i < 16; ++i)
    ol[lo][w * 32 + (i & 3) + 8 * (i >> 2) + 4 * hi] = acc[i];
  __syncthreads();
  for (int u = tid; u < 1024; u += 256) {
    int s = u >> 5, c = (u & 31) * 4;
    float4 ob = *(const float4*)(out_b + d0 + c);
    float4 o;
    o.x = ol[s][c + 0] + ob.x;
    o.y = ol[s][c + 1] + ob.y;
    o.z = ol[s][c + 2] + ob.z;
    o.w = ol[s][c + 3] + ob.w;
    *(float4*)(out + (size_t)(s0 + s) * 1024 + d0 + c) = o;
  }
}

extern "C" void kernel_launch(void* const* d_in, const int* in_sizes, int n_in,
                              void* d_out, int out_size, void* d_ws, size_t ws_size,
                              hipStream_t stream) {
  const float* x = (const float*)d_in[0];
  const int* mask = (const int*)d_in[1];
  const float* qkv_u = (const float*)d_in[2];
  const float* qkv_v = (const float*)d_in[3];
  const float* qkv_b = (const float*)d_in[4];
  const float* u_attn = (const float*)d_in[5];
  const float* v_attn = (const float*)d_in[6];
  const float* out_u = (const float*)d_in[7];
  const float* out_v = (const float*)d_in[8];
  const float* out_b = (const float*)d_in[9];
  float* out = (float*)d_out;

  char* w = (char*)d_ws;
  u16* WQT = (u16*)(w + 0);                // 32 KB
  u16* WKT = (u16*)(w + (32 << 10));       // 32 KB
  u16* WVT = (u16*)(w + (64 << 10));       // 32 KB
  float* BQ = (float*)(w + (96 << 10));    // 6 KB
  u16* WOT = (u16*)(w + (104 << 10));      // 32 KB
  u16* UT = (u16*)(w + (136 << 10));       // 64 KB
  u16* OVT = (u16*)(w + (200 << 10));      // 64 KB
  u16* T = (u16*)(w + (1 << 20));          // 512 KB bf16 [8192][32]
  u16* QL = (u16*)(w + (2 << 20));         // 8 MB bf16 [bh][s][32]
  u16* KL = (u16*)(w + (10 << 20));        // 8 MB bf16 [bh][s][32]
  u16* VT = (u16*)(w + (18 << 20));        // 8 MB bf16 [bh][32][s] (tau cols)
  u16* CTX = (u16*)(w + (26 << 20));       // 8 MB bf16 [8192][512]
  u16* YL = (u16*)(w + (34 << 20));        // 512 KB bf16 [8192][32]

  k_prep<<<32, 256, 0, stream>>>(qkv_v, qkv_b, u_attn, v_attn, out_u, qkv_u, out_v,
                                 WQT, WKT, WVT, BQ, WOT, UT, OVT);
  k_proj<<<256, 256, 0, stream>>>(x, UT, T);
  k_lowproj<<<1024, 256, 0, stream>>>(T, WQT, WKT, WVT, BQ, QL, KL, VT);
  k_attn<<<2048, 256, 0, stream>>>(QL, KL, VT, mask, CTX);
  k_epi1<<<256, 256, 0, stream>>>(CTX, WOT, YL);
  k_epi2<<<2048, 256, 0, stream>>>(YL, OVT, out_b, out);
}

// Round 7
// 132.346 us; speedup vs baseline: 1.2266x; 1.2266x over previous
//
#include <hip/hip_runtime.h>
#include <hip/hip_bf16.h>

typedef unsigned int u32;
typedef unsigned short u16;
typedef __attribute__((ext_vector_type(8))) __bf16 bf16x8;
typedef __attribute__((ext_vector_type(16))) float f32x16;
typedef __attribute__((ext_vector_type(2))) unsigned int u32x2;

// log2(e)/sqrt(32): folds exp->exp2 and 1/sqrt(rank) into Q.
#define QSCALE 0.25505418f
#define MFMA __builtin_amdgcn_mfma_f32_32x32x16_bf16

static __device__ __forceinline__ u16 f2b(float f) {
  __hip_bfloat16 h = __float2bfloat16(f);
  return *reinterpret_cast<u16*>(&h);
}
// HW packed f32->bf16 (RNE). Single VALU instr vs ~6-op SW emulation.
static __device__ __forceinline__ u32 cvtpk(float lo, float hi) {
  u32 r;
  asm("v_cvt_pk_bf16_f32 %0, %1, %2" : "=v"(r) : "v"(lo), "v"(hi));
  return r;
}

static __device__ __forceinline__ float xhalf_sum(float v) {
#if __has_builtin(__builtin_amdgcn_permlane32_swap)
  u32 a = __float_as_uint(v);
  u32x2 r = __builtin_amdgcn_permlane32_swap(a, a, false, false);
  return __uint_as_float(r[0]) + __uint_as_float(r[1]);
#else
  return v + __shfl_xor(v, 32);
#endif
}

// tau: involution on [0,32): swap bits 0,1 of the 4-group index.
// VF columns stored in tau order so P-regs feed the PV B-fragment directly.
static __device__ __forceinline__ int tau(int p) {
  int g = p >> 2;
  int gk = (g & 4) | ((g & 1) << 1) | ((g >> 1) & 1);
  return (gk << 2) | (p & 3);
}

// ---------------------------------------------------------------------------
// K1: fold weights. WQT/WKT/WVT[h][r][rp] (bf16, pre-transposed for A-frags),
// BQKV f32 (bq|bk|bv), WOT[r2][hr] bf16, UT[r][k]=qkv_u^T bf16,
// OVT[d][r]=out_v^T bf16.
// ---------------------------------------------------------------------------
__global__ __launch_bounds__(256) void k_prep(const float* __restrict__ qkv_v,
                                              const float* __restrict__ qkv_b,
                                              const float* __restrict__ u_attn,
                                              const float* __restrict__ v_attn,
                                              const float* __restrict__ out_u,
                                              const float* __restrict__ qkv_u,
                                              const float* __restrict__ out_v,
                                              u16* __restrict__ WQT, u16* __restrict__ WKT,
                                              u16* __restrict__ WVT, float* __restrict__ BQKV,
                                              u16* __restrict__ WOT, u16* __restrict__ UT,
                                              u16* __restrict__ OVT) {
  int blk = blockIdx.x;
  int tid = threadIdx.x;
  if (blk < 16) {
    int h = blk;
    int r = tid & 31, g = tid >> 5;
    for (int rp = g; rp < 32; rp += 8) {
      float aq = 0.f, ak = 0.f, av = 0.f;
      for (int d = 0; d < 64; ++d) {
        float u = u_attn[(h * 64 + d) * 32 + r];
        aq += qkv_v[rp * 3072 + h * 64 + d] * u;
        ak += qkv_v[rp * 3072 + 1024 + h * 64 + d] * u;
        av += qkv_v[rp * 3072 + 2048 + h * 64 + d] * u;
      }
      WQT[(h * 32 + r) * 32 + rp] = f2b(aq);
      WKT[(h * 32 + r) * 32 + rp] = f2b(ak);
      WVT[(h * 32 + r) * 32 + rp] = f2b(av);
    }
    for (int rr = g; rr < 32; rr += 8) {
      float a = 0.f;
      for (int d = 0; d < 64; ++d)
        a += v_attn[(h * 32 + rr) * 64 + d] * out_u[(h * 64 + d) * 32 + r];
      WOT[r * 512 + h * 32 + rr] = f2b(a);
    }
    if (tid < 32) {
      float aq = 0.f, ak = 0.f, av = 0.f;
      for (int d = 0; d < 64; ++d) {
        float u = u_attn[(h * 64 + d) * 32 + r];
        aq += qkv_b[h * 64 + d] * u;
        ak += qkv_b[1024 + h * 64 + d] * u;
        av += qkv_b[2048 + h * 64 + d] * u;
      }
      BQKV[h * 32 + r] = aq;
      BQKV[512 + h * 32 + r] = ak;
      BQKV[1024 + h * 32 + r] = av;
    }
  } else if (blk < 24) {
    int kb = (blk - 16) * 128;
    for (int i = tid; i < 4096; i += 256) {
      int r = i >> 7, kl = i & 127;
      UT[r * 1024 + kb + kl] = f2b(qkv_u[(kb + kl) * 32 + r]);
    }
  } else {
    int db = (blk - 24) * 128;
    for (int i = tid; i < 4096; i += 256) {
      int dl = i >> 5, r = i & 31;
      OVT[(db + dl) * 32 + r] = f2b(out_v[r * 1024 + db + dl]);
    }
  }
}

// ---------------------------------------------------------------------------
// K2: T = x @ qkv_u -> bf16 [8192][32]. MFMA, block = 32-row tile, 4 waves
// split K (256 each, 16 steps), LDS reduce.
// ---------------------------------------------------------------------------
__global__ __launch_bounds__(256) void k_proj(const float* __restrict__ x,
                                              const u16* __restrict__ UT,
                                              u16* __restrict__ T) {
  __shared__ float red[4][32][33];
  int tid = threadIdx.x;
  int w = tid >> 6, l = tid & 63, lo = l & 31, hi = l >> 5;
  int m0 = blockIdx.x * 32;
  const float* xp = x + (size_t)(m0 + lo) * 1024 + w * 256 + hi * 8;
  const u16* up = UT + lo * 1024 + w * 256 + hi * 8;
  f32x16 acc = {};
  for (int s = 0; s < 16; ++s) {
    float4 x0 = *(const float4*)(xp);
    float4 x1 = *(const float4*)(xp + 4);
    xp += 16;
    union { bf16x8 v; u32 u[4]; } af;
    af.u[0] = cvtpk(x0.x, x0.y);
    af.u[1] = cvtpk(x0.z, x0.w);
    af.u[2] = cvtpk(x1.x, x1.y);
    af.u[3] = cvtpk(x1.z, x1.w);
    bf16x8 bf = *(const bf16x8*)(up);
    up += 16;
    acc = MFMA(af.v, bf, acc, 0, 0, 0);
  }
#pragma unroll
  for (int i = 0; i < 16; ++i)
    red[w][(i & 3) + 8 * (i >> 2) + 4 * hi][lo] = acc[i];
  __syncthreads();
  int m = tid >> 3, c = (tid & 7) * 4;
  float v0 = red[0][m][c + 0] + red[1][m][c + 0] + red[2][m][c + 0] + red[3][m][c + 0];
  float v1 = red[0][m][c + 1] + red[1][m][c + 1] + red[2][m][c + 1] + red[3][m][c + 1];
  float v2 = red[0][m][c + 2] + red[1][m][c + 2] + red[2][m][c + 2] + red[3][m][c + 2];
  float v3 = red[0][m][c + 3] + red[1][m][c + 3] + red[2][m][c + 3] + red[3][m][c + 3];
  uint2 o;
  o.x = cvtpk(v0, v1);
  o.y = cvtpk(v2, v3);
  *(uint2*)(T + (size_t)(m0 + m) * 32 + c) = o;
}

// ---------------------------------------------------------------------------
// K3: per-head low-rank Q/K/V via MFMA. Wave = one 32-s tile; 6 MFMAs.
// QL [bh][s][32] bf16 (Q scaled, s-major: loaded once per wave in k_attn).
// KF/VF [bh][tile][1024] bf16 FRAGMENT-MAJOR: element (row kappa, col c) of
// the 32x32 tile lives at flat = (c>>4)*512 + ((c>>3)&1)*256 + kappa*8 + (c&7),
// so k_attn lane l reads its whole bf16x8 fragment at base + l*8 (+512) --
// fully coalesced 1KB bursts instead of 64B/4KB-stride scatters (r6: memory
// address-pipe serialization kept all pipes <32% busy).
// VF columns are tau-permuted within each 32-key tile (see k_attn).
// ---------------------------------------------------------------------------
__global__ __launch_bounds__(256) void k_lowproj(const u16* __restrict__ T,
                                                 const u16* __restrict__ WQT,
                                                 const u16* __restrict__ WKT,
                                                 const u16* __restrict__ WVT,
                                                 const float* __restrict__ BQKV,
                                                 u16* __restrict__ QL, u16* __restrict__ KF,
                                                 u16* __restrict__ VF) {
  __shared__ float vtf[32][132];
  int tid = threadIdx.x;
  int w = tid >> 6, l = tid & 63, lo = l & 31, hi = l >> 5;
  int blk = blockIdx.x;  // 64 bh * 16 sblocks
  int bh = blk >> 4, sb = (blk & 15) * 128;
  int b = bh >> 4, h = bh & 15;
  int s0 = sb + w * 32;

  const u16* wq = WQT + (h * 32 + lo) * 32 + hi * 8;
  const u16* wk = WKT + (h * 32 + lo) * 32 + hi * 8;
  const u16* wv = WVT + (h * 32 + lo) * 32 + hi * 8;
  bf16x8 aq0 = *(const bf16x8*)(wq), aq1 = *(const bf16x8*)(wq + 16);
  bf16x8 ak0 = *(const bf16x8*)(wk), ak1 = *(const bf16x8*)(wk + 16);
  bf16x8 av0 = *(const bf16x8*)(wv), av1 = *(const bf16x8*)(wv + 16);

  const u16* tp = T + (size_t)(b * 2048 + s0 + lo) * 32 + hi * 8;
  bf16x8 tb0 = *(const bf16x8*)(tp), tb1 = *(const bf16x8*)(tp + 16);

  f32x16 cq = {}, ck = {}, cv = {};
  cq = MFMA(aq0, tb0, cq, 0, 0, 0);
  cq = MFMA(aq1, tb1, cq, 0, 0, 0);
  ck = MFMA(ak0, tb0, ck, 0, 0, 0);
  ck = MFMA(ak1, tb1, ck, 0, 0, 0);
  cv = MFMA(av0, tb0, cv, 0, 0, 0);
  cv = MFMA(av1, tb1, cv, 0, 0, 0);

  size_t sg = (size_t)bh * 2048 + s0 + lo;
  size_t tbase = (size_t)bh * 65536 + (size_t)((sb >> 5) + w) * 1024;
  int slp = w * 32 + tau(lo);
#pragma unroll
  for (int g2 = 0; g2 < 4; ++g2) {
    float4 bq4 = *(const float4*)(BQKV + h * 32 + g2 * 8 + 4 * hi);
    float4 bk4 = *(const float4*)(BQKV + 512 + h * 32 + g2 * 8 + 4 * hi);
    float4 bv4 = *(const float4*)(BQKV + 1024 + h * 32 + g2 * 8 + 4 * hi);
    float q0 = (cq[4 * g2 + 0] + bq4.x) * QSCALE;
    float q1 = (cq[4 * g2 + 1] + bq4.y) * QSCALE;
    float q2 = (cq[4 * g2 + 2] + bq4.z) * QSCALE;
    float q3 = (cq[4 * g2 + 3] + bq4.w) * QSCALE;
    uint2 qo; qo.x = cvtpk(q0, q1); qo.y = cvtpk(q2, q3);
    *(uint2*)(QL + sg * 32 + g2 * 8 + 4 * hi) = qo;
    uint2 ko;
    ko.x = cvtpk(ck[4 * g2 + 0] + bk4.x, ck[4 * g2 + 1] + bk4.y);
    ko.y = cvtpk(ck[4 * g2 + 2] + bk4.z, ck[4 * g2 + 3] + bk4.w);
    // fragment-major: cols c0=g2*8+4hi..+3 of key-row lo ->
    // chunk=g2>>1, hif=g2&1, elem offset 4hi
    *(uint2*)(KF + tbase + (g2 >> 1) * 512 + (g2 & 1) * 256 + lo * 8 + 4 * hi) = ko;
    int rbase = g2 * 8 + 4 * hi;
    vtf[rbase + 0][slp] = cv[4 * g2 + 0] + bv4.x;
    vtf[rbase + 1][slp] = cv[4 * g2 + 1] + bv4.y;
    vtf[rbase + 2][slp] = cv[4 * g2 + 2] + bv4.z;
    vtf[rbase + 3][slp] = cv[4 * g2 + 3] + bv4.w;
  }
  __syncthreads();
  for (int u = tid; u < 512; u += 256) {
    int r = u >> 4, su = (u & 15) * 8;
    const float* src = &vtf[r][su];
    uint4 o;
    o.x = cvtpk(src[0], src[1]);
    o.y = cvtpk(src[2], src[3]);
    o.z = cvtpk(src[4], src[5]);
    o.w = cvtpk(src[6], src[7]);
    int c = su & 31, tloc = su >> 5;
    // fragment-major: 8 cols c..c+7 of V^T row r, tile (sb>>5)+tloc
    *(uint4*)(VF + (size_t)bh * 65536 + (size_t)((sb >> 5) + tloc) * 1024 +
              (c >> 4) * 512 + ((c >> 3) & 1) * 256 + r * 8) = o;
  }
}

// ---------------------------------------------------------------------------
// K4: flash attention (swapped-operand 32x32x16 MFMA).
// Fixed-base softmax -> K-partials are ADDITIVE (no max/rescale); 64 key
// tiles split across 2 waves, combined once via LDS. Block = 2 q-tiles x
// 2 K-halves; grid 2048 = 64 bh x 32 q-pairs; XCD swizzle for K/V L2 reuse.
// K/V loads are fragment-major (base + l*8): fully coalesced 1KB bursts.
// Hot loop has zero mask work (pre-scan; general masked loop cold).
// ---------------------------------------------------------------------------
__global__ __launch_bounds__(256) void k_attn(const u16* __restrict__ QL,
                                              const u16* __restrict__ KF,
                                              const u16* __restrict__ VF,
                                              const int* __restrict__ mask,
                                              u16* __restrict__ CTX) {
  __shared__ float pacc[2][64][17];
  __shared__ float pl[2][64];
  __shared__ u32 cls[64][17];
  int tid = threadIdx.x;
  int wave = tid >> 6, l = tid & 63, lo = l & 31, hi = l >> 5;
  int blk = blockIdx.x;
  // XCD-aware decode: xcd = blk & 7 (round-robin dispatch), 256 slots/XCD,
  // 8 bh per XCD, 32 q-pairs per bh.
  int xcd = blk & 7, slot = blk >> 3;
  int bh = xcd * 8 + (slot >> 5);
  int qpair = slot & 31;
  int qi = wave & 1;     // q-tile within pair
  int khalf = wave >> 1; // K-half: tiles [khalf*32, khalf*32+32)
  int qt = qpair * 2 + qi;
  int b = bh >> 4, h = bh & 15;

  const int* mk = mask + b * 2048;

  int q = qt * 32 + lo;
  const u16* qp = QL + (size_t)bh * 65536 + q * 32 + hi * 8;
  bf16x8 qb0 = *(const bf16x8*)(qp);
  bf16x8 qb1 = *(const bf16x8*)(qp + 16);

  size_t fbase = (size_t)bh * 65536 + (size_t)khalf * 32768 + l * 8;
  const u16* kp = KF + fbase;
  const u16* vp = VF + fbase;

  f32x16 acc = {};
  float l_run = 0.f;

  // one-time mask pre-scan: is every key unmasked?
  int mall = 1;
  for (int i = l; i < 2048; i += 64) mall &= (mk[i] != 0) ? 1 : 0;

  if (__all(mall)) {
    // hot path: no mask loads, no ballot
#pragma unroll 1
    for (int kt = 0; kt < 32; ++kt) {
      bf16x8 ka0 = *(const bf16x8*)(kp);
      bf16x8 ka1 = *(const bf16x8*)(kp + 512);
      kp += 1024;
      f32x16 sc = {};
      sc = MFMA(ka0, qb0, sc, 0, 0, 0);
      sc = MFMA(ka1, qb1, sc, 0, 0, 0);
      bf16x8 va0 = *(const bf16x8*)(vp);
      bf16x8 va1 = *(const bf16x8*)(vp + 512);
      vp += 1024;
      union { bf16x8 v; u32 u[4]; } fa;
      float a0 = __builtin_amdgcn_exp2f(sc[0]);
      float a1 = __builtin_amdgcn_exp2f(sc[1]);
      float a2 = __builtin_amdgcn_exp2f(sc[2]);
      float a3 = __builtin_amdgcn_exp2f(sc[3]);
      fa.u[0] = cvtpk(a0, a1);
      fa.u[1] = cvtpk(a2, a3);
      float t0 = (a0 + a1) + (a2 + a3);
      a0 = __builtin_amdgcn_exp2f(sc[4]);
      a1 = __builtin_amdgcn_exp2f(sc[5]);
      a2 = __builtin_amdgcn_exp2f(sc[6]);
      a3 = __builtin_amdgcn_exp2f(sc[7]);
      fa.u[2] = cvtpk(a0, a1);
      fa.u[3] = cvtpk(a2, a3);
      float t1 = (a0 + a1) + (a2 + a3);
      acc = MFMA(va0, fa.v, acc, 0, 0, 0);
      union { bf16x8 v; u32 u[4]; } fc;
      a0 = __builtin_amdgcn_exp2f(sc[8]);
      a1 = __builtin_amdgcn_exp2f(sc[9]);
      a2 = __builtin_amdgcn_exp2f(sc[10]);
      a3 = __builtin_amdgcn_exp2f(sc[11]);
      fc.u[0] = cvtpk(a0, a1);
      fc.u[1] = cvtpk(a2, a3);
      float t2 = (a0 + a1) + (a2 + a3);
      a0 = __builtin_amdgcn_exp2f(sc[12]);
      a1 = __builtin_amdgcn_exp2f(sc[13]);
      a2 = __builtin_amdgcn_exp2f(sc[14]);
      a3 = __builtin_amdgcn_exp2f(sc[15]);
      fc.u[2] = cvtpk(a0, a1);
      fc.u[3] = cvtpk(a2, a3);
      float t3 = (a0 + a1) + (a2 + a3);
      acc = MFMA(va1, fc.v, acc, 0, 0, 0);
      l_run += (t0 + t1) + (t2 + t3);
    }
  } else {
    // cold path: general masked loop (per-tile ballot + score clamp)
    const int* mp = mk + khalf * 1024 + lo;
#pragma unroll 1
    for (int kt = 0; kt < 32; ++kt) {
      unsigned long long bm = __ballot(mp[0] != 0);
      mp += 32;
      bf16x8 ka0 = *(const bf16x8*)(kp);
      bf16x8 ka1 = *(const bf16x8*)(kp + 512);
      kp += 1024;
      f32x16 sc = {};
      sc = MFMA(ka0, qb0, sc, 0, 0, 0);
      sc = MFMA(ka1, qb1, sc, 0, 0, 0);
      u32 km = (u32)bm;
#pragma unroll
      for (int i = 0; i < 16; ++i) {
        int key = (i & 3) + 8 * (i >> 2) + 4 * hi;
        if (!((km >> key) & 1)) sc[i] = -3.0e38f;
      }
      bf16x8 va0 = *(const bf16x8*)(vp);
      bf16x8 va1 = *(const bf16x8*)(vp + 512);
      vp += 1024;
      union { bf16x8 v; u32 u[4]; } fa;
      float a0 = __builtin_amdgcn_exp2f(sc[0]);
      float a1 = __builtin_amdgcn_exp2f(sc[1]);
      float a2 = __builtin_amdgcn_exp2f(sc[2]);
      float a3 = __builtin_amdgcn_exp2f(sc[3]);
      fa.u[0] = cvtpk(a0, a1);
      fa.u[1] = cvtpk(a2, a3);
      float t0 = (a0 + a1) + (a2 + a3);
      a0 = __builtin_amdgcn_exp2f(sc[4]);
      a1 = __builtin_amdgcn_exp2f(sc[5]);
      a2 = __builtin_amdgcn_exp2f(sc[6]);
      a3 = __builtin_amdgcn_exp2f(sc[7]);
      fa.u[2] = cvtpk(a0, a1);
      fa.u[3] = cvtpk(a2, a3);
      float t1 = (a0 + a1) + (a2 + a3);
      acc = MFMA(va0, fa.v, acc, 0, 0, 0);
      union { bf16x8 v; u32 u[4]; } fc;
      a0 = __builtin_amdgcn_exp2f(sc[8]);
      a1 = __builtin_amdgcn_exp2f(sc[9]);
      a2 = __builtin_amdgcn_exp2f(sc[10]);
      a3 = __builtin_amdgcn_exp2f(sc[11]);
      fc.u[0] = cvtpk(a0, a1);
      fc.u[1] = cvtpk(a2, a3);
      float t2 = (a0 + a1) + (a2 + a3);
      a0 = __builtin_amdgcn_exp2f(sc[12]);
      a1 = __builtin_amdgcn_exp2f(sc[13]);
      a2 = __builtin_amdgcn_exp2f(sc[14]);
      a3 = __builtin_amdgcn_exp2f(sc[15]);
      fc.u[2] = cvtpk(a0, a1);
      fc.u[3] = cvtpk(a2, a3);
      float t3 = (a0 + a1) + (a2 + a3);
      acc = MFMA(va1, fc.v, acc, 0, 0, 0);
      l_run += (t0 + t1) + (t2 + t3);
    }
  }

  // combine K-halves: khalf=1 publishes partials, khalf=0 reduces.
  if (khalf) {
#pragma unroll
    for (int i = 0; i < 16; ++i) pacc[qi][l][i] = acc[i];
    pl[qi][l] = l_run;
  }
  __syncthreads();
  if (!khalf) {
#pragma unroll
    for (int i = 0; i < 16; ++i) acc[i] += pacc[qi][l][i];
    l_run += pl[qi][l];
    l_run = xhalf_sum(l_run);  // other 16 keys of this q live in partner half
    float inv = 1.0f / l_run;
    int qloc = qi * 32 + lo;
#pragma unroll
    for (int g2 = 0; g2 < 4; ++g2) {
      cls[qloc][g2 * 4 + 2 * hi] = cvtpk(acc[4 * g2 + 0] * inv, acc[4 * g2 + 1] * inv);
      cls[qloc][g2 * 4 + 2 * hi + 1] = cvtpk(acc[4 * g2 + 2] * inv, acc[4 * g2 + 3] * inv);
    }
  }
  __syncthreads();
  // write 64 q-rows x 32 bf16: one uint4 per thread
  int s_loc = tid >> 2, quad = tid & 3;
  int srow = qpair * 64 + s_loc;
  const u32* src = &cls[s_loc][quad * 4];
  uint4 v0;
  v0.x = src[0]; v0.y = src[1]; v0.z = src[2]; v0.w = src[3];
  u16* dst = CTX + (((size_t)(b * 2048 + srow)) * 16 + h) * 32 + quad * 8;
  *(uint4*)(dst) = v0;
}

// ---------------------------------------------------------------------------
// K5a: ylow[s][r2] = ctx[s][0:512] @ WOT^T. Block = 32-row tile, 4-way K
// split, LDS reduce, bf16 out.
// ---------------------------------------------------------------------------
__global__ __launch_bounds__(256) void k_epi1(const u16* __restrict__ CTX,
                                              const u16* __restrict__ WOT,
                                              u16* __restrict__ YL) {
  __shared__ float red[4][32][33];
  int tid = threadIdx.x;
  int w = tid >> 6, l = tid & 63, lo = l & 31, hi = l >> 5;
  int s0 = blockIdx.x * 32;
  const u16* cp = CTX + (size_t)(s0 + lo) * 512 + w * 128 + hi * 8;
  const u16* wp = WOT + lo * 512 + w * 128 + hi * 8;
  f32x16 acc = {};
  for (int st = 0; st < 8; ++st) {
    bf16x8 a = *(const bf16x8*)(cp);
    bf16x8 bb = *(const bf16x8*)(wp);
    cp += 16;
    wp += 16;
    acc = MFMA(a, bb, acc, 0, 0, 0);
  }
#pragma unroll
  for (int i = 0; i < 16; ++i)
    red[w][(i & 3) + 8 * (i >> 2) + 4 * hi][lo] = acc[i];
  __syncthreads();
  int m = tid >> 3, c = (tid & 7) * 4;
  float v0 = red[0][m][c + 0] + red[1][m][c + 0] + red[2][m][c + 0] + red[3][m][c + 0];
  float v1 = red[0][m][c + 1] + red[1][m][c + 1] + red[2][m][c + 1] + red[3][m][c + 1];
  float v2 = red[0][m][c + 2] + red[1][m][c + 2] + red[2][m][c + 2] + red[3][m][c + 2];
  float v3 = red[0][m][c + 3] + red[1][m][c + 3] + red[2][m][c + 3] + red[3][m][c + 3];
  uint2 o;
  o.x = cvtpk(v0, v1);
  o.y = cvtpk(v2, v3);
  *(uint2*)(YL + (size_t)(s0 + m) * 32 + c) = o;
}

// ---------------------------------------------------------------------------
// K5b: out = ylow @ out_v + out_b. Block = 32 s x 128 d (4 waves, one d-sub
// tile each), LDS-staged coalesced f32 stores.
// ---------------------------------------------------------------------------
__global__ __launch_bounds__(256) void k_epi2(const u16* __restrict__ YL,
                                              const u16* __restrict__ OVT,
                                              const float* __restrict__ out_b,
                                              float* __restrict__ out) {
  __shared__ float ol[32][133];
  int tid = threadIdx.x;
  int w = tid >> 6, l = tid & 63, lo = l & 31, hi = l >> 5;
  int blk = blockIdx.x;  // 256 s-tiles x 8 d-tiles
  int s0 = (blk >> 3) * 32;
  int d0 = (blk & 7) * 128;
  int dw = d0 + w * 32;
  const u16* ap = OVT + (size_t)(dw + lo) * 32 + hi * 8;
  bf16x8 a0 = *(const bf16x8*)(ap), a1 = *(const bf16x8*)(ap + 16);
  const u16* bp = YL + (size_t)(s0 + lo) * 32 + hi * 8;
  bf16x8 b0 = *(const bf16x8*)(bp), b1 = *(const bf16x8*)(bp + 16);
  f32x16 acc = {};
  acc = MFMA(a0, b0, acc, 0, 0, 0);
  acc = MFMA(a1, b1, acc, 0, 0, 0);
#pragma unroll
  for (int i = 0; i < 16; ++i)
    ol[lo][w * 32 + (i & 3) + 8 * (i >> 2) + 4 * hi] = acc[i];
  __syncthreads();
  for (int u = tid; u < 1024; u += 256) {
    int s = u >> 5, c = (u & 31) * 4;
    float4 ob = *(const float4*)(out_b + d0 + c);
    float4 o;
    o.x = ol[s][c + 0] + ob.x;
    o.y = ol[s][c + 1] + ob.y;
    o.z = ol[s][c + 2] + ob.z;
    o.w = ol[s][c + 3] + ob.w;
    *(float4*)(out + (size_t)(s0 + s) * 1024 + d0 + c) = o;
  }
}

extern "C" void kernel_launch(void* const* d_in, const int* in_sizes, int n_in,
                              void* d_out, int out_size, void* d_ws, size_t ws_size,
                              hipStream_t stream) {
  const float* x = (const float*)d_in[0];
  const int* mask = (const int*)d_in[1];
  const float* qkv_u = (const float*)d_in[2];
  const float* qkv_v = (const float*)d_in[3];
  const float* qkv_b = (const float*)d_in[4];
  const float* u_attn = (const float*)d_in[5];
  const float* v_attn = (const float*)d_in[6];
  const float* out_u = (const float*)d_in[7];
  const float* out_v = (const float*)d_in[8];
  const float* out_b = (const float*)d_in[9];
  float* out = (float*)d_out;

  char* w = (char*)d_ws;
  u16* WQT = (u16*)(w + 0);                // 32 KB
  u16* WKT = (u16*)(w + (32 << 10));       // 32 KB
  u16* WVT = (u16*)(w + (64 << 10));       // 32 KB
  float* BQ = (float*)(w + (96 << 10));    // 6 KB
  u16* WOT = (u16*)(w + (104 << 10));      // 32 KB
  u16* UT = (u16*)(w + (136 << 10));       // 64 KB
  u16* OVT = (u16*)(w + (200 << 10));      // 64 KB
  u16* T = (u16*)(w + (1 << 20));          // 512 KB bf16 [8192][32]
  u16* QL = (u16*)(w + (2 << 20));         // 8 MB bf16 [bh][s][32]
  u16* KF = (u16*)(w + (10 << 20));        // 8 MB bf16 [bh][tile][frag]
  u16* VF = (u16*)(w + (18 << 20));        // 8 MB bf16 [bh][tile][frag] (tau)
  u16* CTX = (u16*)(w + (26 << 20));       // 8 MB bf16 [8192][512]
  u16* YL = (u16*)(w + (34 << 20));        // 512 KB bf16 [8192][32]

  k_prep<<<32, 256, 0, stream>>>(qkv_v, qkv_b, u_attn, v_attn, out_u, qkv_u, out_v,
                                 WQT, WKT, WVT, BQ, WOT, UT, OVT);
  k_proj<<<256, 256, 0, stream>>>(x, UT, T);
  k_lowproj<<<1024, 256, 0, stream>>>(T, WQT, WKT, WVT, BQ, QL, KF, VF);
  k_attn<<<2048, 256, 0, stream>>>(QL, KF, VF, mask, CTX);
  k_epi1<<<256, 256, 0, stream>>>(CTX, WOT, YL);
  k_epi2<<<2048, 256, 0, stream>>>(YL, OVT, out_b, out);
}